// Round 1
// baseline (139.865 us; speedup 1.0000x reference)
//
#include <hip/hip_runtime.h>
#include <math.h>

#define NNODES 20000
#define NEDGES 640000
#define C 128

// K1: 256 blocks x 1024 threads
#define NB1 256
#define BT 1024

// K2: LDS-free edge scatter + fused final. 320 blocks x 1024 threads.
#define NB2 320
#define BT2 1024

// packed per-node GLOBAL u64 atomic:
//   bits[40,64) = edge count, bits[0,40) = fix16 sum, biased 2^20 per edge.
// |t| << 16 (so |fix| << 2^20); even 640000 edges on one node:
//   640000 * (2^20 + |fix|) < 2^40, count < 2^24.  No overflow, no carry
//   into the count field. Integer adds => order-independent => deterministic.
#define SUM_BITS 40
#define FIX_BIAS (1 << 20)

// ---------------------------------------------------------------------------
// K1: fused weight-collapse + per-node dots (R6-verified phase A unchanged).
// Additionally zeroes acc[] and the ticket counter (must happen every
// iteration: harness re-poisons the workspace).
//   u[k]=f_w[k,:].cls  v[k]=f_w[128+k,:].cls  p[k]=g_w[k,:].v  q[k]=g_w[128+k,:].v
//   scal={g_b.v, g_w[256,:].v, f_b.cls+cls_b}
//   xu[n]=x[n].u  xp[n]=x[n].p  r[n]=x[n].q
// ---------------------------------------------------------------------------
__global__ void __launch_bounds__(BT)
k_node(const float* __restrict__ x,
       const float* __restrict__ g_w, const float* __restrict__ g_b,
       const float* __restrict__ f_w, const float* __restrict__ f_b,
       const float* __restrict__ cls_w, const float* __restrict__ cls_b,
       float* __restrict__ xu, float* __restrict__ xp,
       float* __restrict__ r, float* __restrict__ scal,
       unsigned long long* __restrict__ acc, unsigned int* __restrict__ done)
{
    __shared__ float csh[C], vsh[C], ush[C], psh[C], qsh[C];
    __shared__ float red[BT];
    const int tid = threadIdx.x;

    // ---- zero the global accumulator + ticket (stream-ordered before K2) ----
    {
        int i = blockIdx.x * BT + tid;
        if (i < NNODES) acc[i] = 0ull;
        if (blockIdx.x == 0 && tid == 0) *done = 0u;
    }

    // ---- phase A (verified in R6) ----
    {
        int pair = tid >> 2;      // 0..255 : (k,h)
        int prt  = tid & 3;       // 32-channel segment
        int k = pair & 127;
        int h = pair >> 7;

        if (tid < C) csh[tid] = cls_w[tid];
        __syncthreads();

        const float4* fw4 = (const float4*)f_w;
        const float4* gw4 = (const float4*)g_w;
        const float4* cs4 = (const float4*)csh;

        {   // u (h=0) / v (h=1)
            const float4* row = fw4 + (size_t)(h * C + k) * (C / 4) + prt * 8;
            const float4* cc  = cs4 + prt * 8;
            float s = 0.f;
            #pragma unroll
            for (int j = 0; j < 8; ++j) {
                float4 a = row[j], c = cc[j];
                s += a.x * c.x + a.y * c.y + a.z * c.z + a.w * c.w;
            }
            red[tid] = s;
        }
        __syncthreads();
        if (prt == 0) {
            float tot = red[tid] + red[tid + 1] + red[tid + 2] + red[tid + 3];
            if (h == 0) ush[k] = tot; else vsh[k] = tot;
        }
        __syncthreads();

        const float4* vs4 = (const float4*)vsh;
        {   // p (h=0) / q (h=1)
            const float4* row = gw4 + (size_t)(h * C + k) * (C / 4) + prt * 8;
            const float4* vv  = vs4 + prt * 8;
            float s = 0.f;
            #pragma unroll
            for (int j = 0; j < 8; ++j) {
                float4 a = row[j], c = vv[j];
                s += a.x * c.x + a.y * c.y + a.z * c.z + a.w * c.w;
            }
            red[tid] = s;
        }
        __syncthreads();
        if (prt == 0) {
            float tot = red[tid] + red[tid + 1] + red[tid + 2] + red[tid + 3];
            if (h == 0) psh[k] = tot; else qsh[k] = tot;
        }
        __syncthreads();   // separates red reads above from red overwrite below

        // three 128-length scalar dots via LDS tree (all blocks, identical)
        if (tid < C) red[tid] = g_b[tid] * vsh[tid];
        __syncthreads();
        for (int s = 64; s > 0; s >>= 1) { if (tid < s) red[tid] += red[tid + s]; __syncthreads(); }
        if (tid == 0) scal[0] = red[0];
        __syncthreads();
        if (tid < C) red[tid] = g_w[256 * C + tid] * vsh[tid];
        __syncthreads();
        for (int s = 64; s > 0; s >>= 1) { if (tid < s) red[tid] += red[tid + s]; __syncthreads(); }
        if (tid == 0) scal[1] = red[0];
        __syncthreads();
        if (tid < C) red[tid] = f_b[tid] * csh[tid];
        __syncthreads();
        for (int s = 64; s > 0; s >>= 1) { if (tid < s) red[tid] += red[tid + s]; __syncthreads(); }
        if (tid == 0) scal[2] = red[0] + cls_b[0];
        __syncthreads();
    }

    // ---- phase B: wave-per-node dots ----
    {
        int w = tid >> 6, lane = tid & 63;
        int gwave = blockIdx.x * (BT / 64) + w;        // 0..4095
        float2 uu = ((const float2*)ush)[lane];
        float2 pp = ((const float2*)psh)[lane];
        float2 qq = ((const float2*)qsh)[lane];

        for (int n = gwave; n < NNODES; n += NB1 * (BT / 64)) {
            float2 xx = ((const float2*)(x + (size_t)n * C))[lane];
            float du = xx.x * uu.x + xx.y * uu.y;
            float dp = xx.x * pp.x + xx.y * pp.y;
            float dq = xx.x * qq.x + xx.y * qq.y;
            for (int off = 32; off > 0; off >>= 1) {
                du += __shfl_down(du, off);
                dp += __shfl_down(dp, off);
                dq += __shfl_down(dq, off);
            }
            if (lane == 0) { xu[n] = du; xp[n] = dp; r[n] = dq; }
        }
    }
}

// ---------------------------------------------------------------------------
// K2: LDS-free per-edge scatter via packed u64 GLOBAL atomics + fused final.
// Last block (ticket) reads acc and produces the outputs — removes the
// 10.24 MB part-buffer write + 10.24 MB read and one whole dispatch.
// ---------------------------------------------------------------------------
__global__ void __launch_bounds__(BT2)
k_edge_final(const int* __restrict__ ei, const float* __restrict__ attr,
             const float* __restrict__ r, const float* __restrict__ scal,
             const float* __restrict__ xu, const float* __restrict__ xp,
             unsigned long long* __restrict__ acc,
             unsigned int* __restrict__ done,
             float* __restrict__ out)
{
    __shared__ unsigned int ticket;
    const int tid = threadIdx.x;
    const float gev = scal[1];

    for (int e = blockIdx.x * BT2 + tid; e < NEDGES; e += NB2 * BT2) {
        int s = ei[e];            // src
        int d = ei[NEDGES + e];   // dst
        float t = r[s] + attr[e] * gev;
        int fix = __float2int_rn(t * 65536.0f);
        unsigned long long add = (1ull << SUM_BITS)
                               | (unsigned long long)(unsigned int)(fix + FIX_BIAS);
        atomicAdd(&acc[d], add);
    }

    // __syncthreads() drains this block's outstanding atomics (compiler emits
    // s_waitcnt vmcnt(0) before s_barrier); ticket order then guarantees the
    // last block observes every other block's completed atomics.
    __syncthreads();
    if (tid == 0) {
        __threadfence();                       // release
        ticket = atomicAdd(done, 1u);
    }
    __syncthreads();
    if (ticket != NB2 - 1) return;
    __threadfence();                           // acquire

    const float s0 = scal[0], s2 = scal[2];
    for (int n = tid; n < NNODES; n += BT2) {
        unsigned long long v = __hip_atomic_load(&acc[n], __ATOMIC_RELAXED,
                                                 __HIP_MEMORY_SCOPE_AGENT);
        unsigned int cnt = (unsigned int)(v >> SUM_BITS);
        long long sumfix = (long long)(v & ((1ull << SUM_BITS) - 1))
                         - ((long long)cnt << 20);
        float sacc = (float)sumfix * (1.0f / 65536.0f);
        float cmax = fmaxf((float)cnt, 1.0f);
        float cfac = (cnt > 0) ? 1.0f : 0.0f;
        float logit = xu[n] + cfac * (xp[n] + s0) + sacc / cmax + s2;
        float pr = 1.0f / (1.0f + expf(-logit));
        out[n] = (pr > 0.5f) ? 1.0f : 0.0f;
        out[NNODES + n] = pr;
    }
}

extern "C" void kernel_launch(void* const* d_in, const int* in_sizes, int n_in,
                              void* d_out, int out_size, void* d_ws, size_t ws_size,
                              hipStream_t stream) {
    const float* x_a       = (const float*)d_in[0];
    const int*   ei        = (const int*)d_in[1];    // [2, E]
    const float* edge_attr = (const float*)d_in[2];  // [E, 1]
    const float* g_w       = (const float*)d_in[3];  // [257,128]
    const float* g_b       = (const float*)d_in[4];  // [128]
    const float* f_w       = (const float*)d_in[5];  // [256,128]
    const float* f_b       = (const float*)d_in[6];  // [128]
    const float* cls_w     = (const float*)d_in[7];  // [128,1]
    const float* cls_b     = (const float*)d_in[8];  // [1]
    float* out = (float*)d_out;

    // workspace layout: acc (8B-aligned at ws base), then node scalars
    unsigned long long* acc = (unsigned long long*)d_ws;       // N u64 = 160 KB
    float* xu   = (float*)(acc + NNODES);                      // N
    float* xp   = xu + NNODES;                                 // N
    float* r    = xp + NNODES;                                 // N
    float* scal = r + NNODES;                                  // 4
    unsigned int* done = (unsigned int*)(scal + 4);            // 1

    k_node<<<NB1, BT, 0, stream>>>(x_a, g_w, g_b, f_w, f_b, cls_w, cls_b,
                                   xu, xp, r, scal, acc, done);

    k_edge_final<<<NB2, BT2, 0, stream>>>(ei, edge_attr, r, scal, xu, xp,
                                          acc, done, out);
}

// Round 3
// 104.142 us; speedup vs baseline: 1.3430x; 1.3430x over previous
//
#include <hip/hip_runtime.h>
#include <math.h>

#define NNODES 20000
#define NEDGES 640000
#define C 128

// K1: 256 blocks x 1024 threads
#define NB1 256
#define BT 1024

// k_edge: 128 blocks x 1024 threads, 80 KB LDS (<=2 blocks/CU)
#define NB 128

// packed per-edge LDS atomic: bits[26,32)=count, bits[0,26)=fix16 sum biased 2^19/edge
// per-(block,node) count mean 0.25, max ~10 << 63; per-edge term < 2^20, sum << 2^26.
#define CNT_SHIFT 26
#define EDGE_BIAS (1 << 19)
#define SUM_MASK 0x03FFFFFFu

// ---------------------------------------------------------------------------
// K1: fused weight-collapse + per-node dots. 256 blocks x 1024 threads.
// R2: LDS-tree reductions replaced by wave-synchronous quad __shfl_down
// (phase A barrier count 35 -> 3); the three 128-length scalar dots are
// computed ONLY by block 0 (three parallel waves, shfl reduce, no barriers).
//   u[k]=f_w[k,:].cls  v[k]=f_w[128+k,:].cls  p[k]=g_w[k,:].v  q[k]=g_w[128+k,:].v
//   scal={g_b.v, g_w[256,:].v, f_b.cls+cls_b}
//   xu[n]=x[n].u  xp[n]=x[n].p  r[n]=x[n].q
// ---------------------------------------------------------------------------
__global__ void __launch_bounds__(BT)
k_node(const float* __restrict__ x,
       const float* __restrict__ g_w, const float* __restrict__ g_b,
       const float* __restrict__ f_w, const float* __restrict__ f_b,
       const float* __restrict__ cls_w, const float* __restrict__ cls_b,
       float* __restrict__ xu, float* __restrict__ xp,
       float* __restrict__ r, float* __restrict__ scal)
{
    __shared__ float csh[C], vsh[C], ush[C], psh[C], qsh[C];
    const int tid = threadIdx.x;
    const int pair = tid >> 2;      // 0..255 : (k,h)
    const int prt  = tid & 3;       // 32-channel segment (4 lanes of one quad)
    const int k = pair & 127;
    const int h = pair >> 7;

    if (tid < C) csh[tid] = cls_w[tid];
    __syncthreads();                                   // barrier 1

    const float4* fw4 = (const float4*)f_w;
    const float4* gw4 = (const float4*)g_w;
    const float4* cs4 = (const float4*)csh;

    {   // u (h=0) / v (h=1): quad-parallel dot, quad shfl reduce (same wave)
        const float4* row = fw4 + (size_t)(h * C + k) * (C / 4) + prt * 8;
        const float4* cc  = cs4 + prt * 8;
        float s = 0.f;
        #pragma unroll
        for (int j = 0; j < 8; ++j) {
            float4 a = row[j], c = cc[j];
            s += a.x * c.x + a.y * c.y + a.z * c.z + a.w * c.w;
        }
        s += __shfl_down(s, 2);
        s += __shfl_down(s, 1);
        if (prt == 0) { if (h == 0) ush[k] = s; else vsh[k] = s; }
    }
    __syncthreads();                                   // barrier 2 (vsh ready)

    const float4* vs4 = (const float4*)vsh;
    {   // p (h=0) / q (h=1)
        const float4* row = gw4 + (size_t)(h * C + k) * (C / 4) + prt * 8;
        const float4* vv  = vs4 + prt * 8;
        float s = 0.f;
        #pragma unroll
        for (int j = 0; j < 8; ++j) {
            float4 a = row[j], c = vv[j];
            s += a.x * c.x + a.y * c.y + a.z * c.z + a.w * c.w;
        }
        s += __shfl_down(s, 2);
        s += __shfl_down(s, 1);
        if (prt == 0) { if (h == 0) psh[k] = s; else qsh[k] = s; }
    }
    __syncthreads();                                   // barrier 3 (u/p/q ready)

    // three 128-length scalar dots: block 0 only, one wave each, no barriers.
    // vsh/csh are stable (nothing overwrites them below).
    if (blockIdx.x == 0 && tid < 192) {
        int w = tid >> 6, lane = tid & 63;
        float a, b;
        if (w == 0)      { a = g_b[lane] * vsh[lane];          b = g_b[lane + 64] * vsh[lane + 64]; }
        else if (w == 1) { a = g_w[256 * C + lane] * vsh[lane]; b = g_w[256 * C + lane + 64] * vsh[lane + 64]; }
        else             { a = f_b[lane] * csh[lane];          b = f_b[lane + 64] * csh[lane + 64]; }
        float s = a + b;
        for (int off = 32; off > 0; off >>= 1) s += __shfl_down(s, off);
        if (lane == 0) scal[w] = (w == 2) ? s + cls_b[0] : s;
    }

    // ---- phase B: wave-per-node dots ----
    {
        int w = tid >> 6, lane = tid & 63;
        int gwave = blockIdx.x * (BT / 64) + w;        // 0..4095
        float2 uu = ((const float2*)ush)[lane];
        float2 pp = ((const float2*)psh)[lane];
        float2 qq = ((const float2*)qsh)[lane];

        for (int n = gwave; n < NNODES; n += NB1 * (BT / 64)) {
            float2 xx = ((const float2*)(x + (size_t)n * C))[lane];
            float du = xx.x * uu.x + xx.y * uu.y;
            float dp = xx.x * pp.x + xx.y * pp.y;
            float dq = xx.x * qq.x + xx.y * qq.y;
            for (int off = 32; off > 0; off >>= 1) {
                du += __shfl_down(du, off);
                dp += __shfl_down(dp, off);
                dq += __shfl_down(dq, off);
            }
            if (lane == 0) { xu[n] = du; xp[n] = dp; r[n] = dq; }
        }
    }
}

// ---------------------------------------------------------------------------
// K2: per-edge scatter (R0/R5-verified structure, NB=128). Full 20000-entry
// u32 table in LDS (80 KB), ONE LDS atomic per edge, uint4 coalesced flush.
// ---------------------------------------------------------------------------
__global__ void __launch_bounds__(BT)
k_edge(const int* __restrict__ ei, const float* __restrict__ attr,
       const float* __restrict__ r, const float* __restrict__ scal,
       unsigned int* __restrict__ part)
{
    __shared__ unsigned int lacc[NNODES];
    int tid = threadIdx.x;

    uint4* l4 = (uint4*)lacc;
    for (int i = tid; i < NNODES / 4; i += BT) l4[i] = make_uint4(0u, 0u, 0u, 0u);
    __syncthreads();

    float gev = scal[1];
    for (int e = blockIdx.x * BT + tid; e < NEDGES; e += NB * BT) {
        int s = ei[e];            // src
        int d = ei[NEDGES + e];   // dst
        float t = r[s] + attr[e] * gev;
        int fix = __float2int_rn(t * 65536.0f);
        atomicAdd(&lacc[d], (1u << CNT_SHIFT) + (unsigned int)(fix + EDGE_BIAS));
    }
    __syncthreads();

    uint4* mp4 = (uint4*)(part + (size_t)blockIdx.x * NNODES);
    for (int i = tid; i < NNODES / 4; i += BT) mp4[i] = l4[i];
}

// ---------------------------------------------------------------------------
// K3: merge NB partials per node. R2: thread-per-node — each wave instruction
// reads 64 consecutive u32 (256 B, fully coalesced); 128 independent loads
// per thread hide HBM latency. 79 blocks x 256 threads.
// ---------------------------------------------------------------------------
__global__ void __launch_bounds__(256)
k_final(const float* __restrict__ xu, const float* __restrict__ xp,
        const unsigned int* __restrict__ part,
        const float* __restrict__ scal, float* __restrict__ out)
{
    int n = blockIdx.x * 256 + threadIdx.x;
    if (n >= NNODES) return;

    int sumfix = 0, cnt = 0;
    const unsigned int* pb = part + n;
    #pragma unroll 16
    for (int b = 0; b < NB; ++b) {
        unsigned int v = pb[(size_t)b * NNODES];
        int c = (int)(v >> CNT_SHIFT);
        cnt += c;
        sumfix += (int)(v & SUM_MASK) - (c << 19);
    }

    float sacc = (float)sumfix * (1.0f / 65536.0f);
    float cmax = fmaxf((float)cnt, 1.0f);
    float cfac = (cnt > 0) ? 1.0f : 0.0f;
    float logit = xu[n] + cfac * (xp[n] + scal[0]) + sacc / cmax + scal[2];
    float pr = 1.0f / (1.0f + expf(-logit));
    out[n] = (pr > 0.5f) ? 1.0f : 0.0f;
    out[NNODES + n] = pr;
}

extern "C" void kernel_launch(void* const* d_in, const int* in_sizes, int n_in,
                              void* d_out, int out_size, void* d_ws, size_t ws_size,
                              hipStream_t stream) {
    const float* x_a       = (const float*)d_in[0];
    const int*   ei        = (const int*)d_in[1];    // [2, E]
    const float* edge_attr = (const float*)d_in[2];  // [E, 1]
    const float* g_w       = (const float*)d_in[3];  // [257,128]
    const float* g_b       = (const float*)d_in[4];  // [128]
    const float* f_w       = (const float*)d_in[5];  // [256,128]
    const float* f_b       = (const float*)d_in[6];  // [128]
    const float* cls_w     = (const float*)d_in[7];  // [128,1]
    const float* cls_b     = (const float*)d_in[8];  // [1]
    float* out = (float*)d_out;

    // workspace layout: part first (16B-aligned at ws base), then node scalars
    unsigned int* part = (unsigned int*)d_ws;                  // NB*N u32 = 10.24 MB
    float* xu   = (float*)d_ws + (size_t)NB * NNODES;          // N
    float* xp   = xu + NNODES;                                 // N
    float* r    = xp + NNODES;                                 // N
    float* scal = r + NNODES;                                  // 4

    k_node<<<NB1, BT, 0, stream>>>(x_a, g_w, g_b, f_w, f_b, cls_w, cls_b,
                                   xu, xp, r, scal);

    k_edge<<<NB, BT, 0, stream>>>(ei, edge_attr, r, scal, part);

    k_final<<<(NNODES + 255) / 256, 256, 0, stream>>>(xu, xp, part, scal, out);
}

// Round 4
// 102.200 us; speedup vs baseline: 1.3685x; 1.0190x over previous
//
#include <hip/hip_runtime.h>
#include <math.h>

#define NNODES 20000
#define NEDGES 640000
#define C 128

// K1: 256 blocks x 1024 threads
#define NB1 256
#define BT 1024

// k_edge: 128 chunks x 2 half-blocks = 256 blocks x 1024 threads, 40 KB LDS.
// Sibling halves of a chunk are blocks b and b+128 -> same XCD (b%8), so the
// second sibling's ei/attr read hits that XCD's L2.
#define NCHUNK 128
#define EPC (NEDGES / NCHUNK)   // 5000 edges per chunk
#define HALFN (NNODES / 2)      // 10000 nodes per half-table

// packed per-edge LDS atomic: bits[26,32)=count, bits[0,26)=fix16 sum biased 2^19/edge
// per-(half-block,node) count ~Poisson(0.25), max ~8 << 63; per-edge term < 2^20,
// sum < 8*2^20 << 2^26.
#define CNT_SHIFT 26
#define EDGE_BIAS (1 << 19)
#define SUM_MASK 0x03FFFFFFu

// ---------------------------------------------------------------------------
// K1: fused weight-collapse + per-node dots (R3-verified). 256 x 1024.
//   u[k]=f_w[k,:].cls  v[k]=f_w[128+k,:].cls  p[k]=g_w[k,:].v  q[k]=g_w[128+k,:].v
//   scal={g_b.v, g_w[256,:].v, f_b.cls+cls_b}
//   xu[n]=x[n].u  xp[n]=x[n].p  r[n]=x[n].q
// ---------------------------------------------------------------------------
__global__ void __launch_bounds__(BT)
k_node(const float* __restrict__ x,
       const float* __restrict__ g_w, const float* __restrict__ g_b,
       const float* __restrict__ f_w, const float* __restrict__ f_b,
       const float* __restrict__ cls_w, const float* __restrict__ cls_b,
       float* __restrict__ xu, float* __restrict__ xp,
       float* __restrict__ r, float* __restrict__ scal)
{
    __shared__ float csh[C], vsh[C], ush[C], psh[C], qsh[C];
    const int tid = threadIdx.x;
    const int pair = tid >> 2;      // 0..255 : (k,h)
    const int prt  = tid & 3;       // 32-channel segment (4 lanes of one quad)
    const int k = pair & 127;
    const int h = pair >> 7;

    if (tid < C) csh[tid] = cls_w[tid];
    __syncthreads();                                   // barrier 1

    const float4* fw4 = (const float4*)f_w;
    const float4* gw4 = (const float4*)g_w;
    const float4* cs4 = (const float4*)csh;

    {   // u (h=0) / v (h=1): quad-parallel dot, quad shfl reduce (same wave)
        const float4* row = fw4 + (size_t)(h * C + k) * (C / 4) + prt * 8;
        const float4* cc  = cs4 + prt * 8;
        float s = 0.f;
        #pragma unroll
        for (int j = 0; j < 8; ++j) {
            float4 a = row[j], c = cc[j];
            s += a.x * c.x + a.y * c.y + a.z * c.z + a.w * c.w;
        }
        s += __shfl_down(s, 2);
        s += __shfl_down(s, 1);
        if (prt == 0) { if (h == 0) ush[k] = s; else vsh[k] = s; }
    }
    __syncthreads();                                   // barrier 2 (vsh ready)

    const float4* vs4 = (const float4*)vsh;
    {   // p (h=0) / q (h=1)
        const float4* row = gw4 + (size_t)(h * C + k) * (C / 4) + prt * 8;
        const float4* vv  = vs4 + prt * 8;
        float s = 0.f;
        #pragma unroll
        for (int j = 0; j < 8; ++j) {
            float4 a = row[j], c = vv[j];
            s += a.x * c.x + a.y * c.y + a.z * c.z + a.w * c.w;
        }
        s += __shfl_down(s, 2);
        s += __shfl_down(s, 1);
        if (prt == 0) { if (h == 0) psh[k] = s; else qsh[k] = s; }
    }
    __syncthreads();                                   // barrier 3 (u/p/q ready)

    // three 128-length scalar dots: block 0 only, one wave each, no barriers.
    if (blockIdx.x == 0 && tid < 192) {
        int w = tid >> 6, lane = tid & 63;
        float a, b;
        if (w == 0)      { a = g_b[lane] * vsh[lane];          b = g_b[lane + 64] * vsh[lane + 64]; }
        else if (w == 1) { a = g_w[256 * C + lane] * vsh[lane]; b = g_w[256 * C + lane + 64] * vsh[lane + 64]; }
        else             { a = f_b[lane] * csh[lane];          b = f_b[lane + 64] * csh[lane + 64]; }
        float s = a + b;
        for (int off = 32; off > 0; off >>= 1) s += __shfl_down(s, off);
        if (lane == 0) scal[w] = (w == 2) ? s + cls_b[0] : s;
    }

    // ---- phase B: wave-per-node dots ----
    {
        int w = tid >> 6, lane = tid & 63;
        int gwave = blockIdx.x * (BT / 64) + w;        // 0..4095
        float2 uu = ((const float2*)ush)[lane];
        float2 pp = ((const float2*)psh)[lane];
        float2 qq = ((const float2*)qsh)[lane];

        for (int n = gwave; n < NNODES; n += NB1 * (BT / 64)) {
            float2 xx = ((const float2*)(x + (size_t)n * C))[lane];
            float du = xx.x * uu.x + xx.y * uu.y;
            float dp = xx.x * pp.x + xx.y * pp.y;
            float dq = xx.x * qq.x + xx.y * qq.y;
            for (int off = 32; off > 0; off >>= 1) {
                du += __shfl_down(du, off);
                dp += __shfl_down(dp, off);
                dq += __shfl_down(dq, off);
            }
            if (lane == 0) { xu[n] = du; xp[n] = dp; r[n] = dq; }
        }
    }
}

// ---------------------------------------------------------------------------
// K2: split-half per-edge scatter. Block b: chunk = b & 127, half = b >> 7.
// 40 KB LDS half-table (10000 nodes); each half-block scans its chunk's 5000
// edges and scatters only dsts in its half. Integer packing identical to the
// verified full-table version -> bit-identical merged sums.
// part layout: part[(chunk*2 + half)*HALFN + idx]  (10.24 MB total, as before)
// ---------------------------------------------------------------------------
__global__ void __launch_bounds__(BT)
k_edge(const int* __restrict__ ei, const float* __restrict__ attr,
       const float* __restrict__ r, const float* __restrict__ scal,
       unsigned int* __restrict__ part)
{
    __shared__ unsigned int lacc[HALFN];
    const int tid = threadIdx.x;
    const int chunk = blockIdx.x & (NCHUNK - 1);
    const int h     = blockIdx.x >> 7;          // 0 or 1
    const int nbase = h * HALFN;

    uint4* l4 = (uint4*)lacc;
    for (int i = tid; i < HALFN / 4; i += BT) l4[i] = make_uint4(0u, 0u, 0u, 0u);
    __syncthreads();

    const float gev = scal[1];
    const int ebase = chunk * EPC;
    for (int i = tid; i < EPC; i += BT) {
        int e = ebase + i;
        int s = ei[e];            // src
        int d = ei[NEDGES + e];   // dst
        unsigned int idx = (unsigned int)(d - nbase);
        if (idx < HALFN) {
            float t = r[s] + attr[e] * gev;
            int fix = __float2int_rn(t * 65536.0f);
            atomicAdd(&lacc[idx], (1u << CNT_SHIFT) + (unsigned int)(fix + EDGE_BIAS));
        }
    }
    __syncthreads();

    uint4* mp4 = (uint4*)(part + (size_t)(chunk * 2 + h) * HALFN);
    for (int i = tid; i < HALFN / 4; i += BT) mp4[i] = l4[i];
}

// ---------------------------------------------------------------------------
// K3: merge 128 chunk-partials per node. Quad-per-node: 4 lanes each merge 32
// chunks (64 B coalesced segments per wave instruction), combined by two
// intra-wave __shfl_down steps. 313 blocks x 256 threads -> full chip.
// ---------------------------------------------------------------------------
__global__ void __launch_bounds__(256)
k_final(const float* __restrict__ xu, const float* __restrict__ xp,
        const unsigned int* __restrict__ part,
        const float* __restrict__ scal, float* __restrict__ out)
{
    int t = threadIdx.x;
    int quad = t >> 2;                 // 0..63
    int prt  = t & 3;
    int n = blockIdx.x * 64 + quad;

    int sumfix = 0, cnt = 0;
    if (n < NNODES) {
        int h   = (n >= HALFN) ? 1 : 0;
        int idx = n - h * HALFN;
        // chunks prt*32 .. prt*32+31
        const unsigned int* pb = part + (size_t)((prt * 32) * 2 + h) * HALFN + idx;
        #pragma unroll
        for (int b = 0; b < NCHUNK / 4; ++b) {
            unsigned int v = pb[(size_t)b * 2 * HALFN];
            int c = (int)(v >> CNT_SHIFT);
            cnt += c;
            sumfix += (int)(v & SUM_MASK) - (c << 19);
        }
    }
    // quad reduce (lanes 4q..4q+3)
    sumfix += __shfl_down(sumfix, 1);
    sumfix += __shfl_down(sumfix, 2);
    cnt    += __shfl_down(cnt, 1);
    cnt    += __shfl_down(cnt, 2);

    if (prt == 0 && n < NNODES) {
        float sacc = (float)sumfix * (1.0f / 65536.0f);
        float cmax = fmaxf((float)cnt, 1.0f);
        float cfac = (cnt > 0) ? 1.0f : 0.0f;
        float logit = xu[n] + cfac * (xp[n] + scal[0]) + sacc / cmax + scal[2];
        float pr = 1.0f / (1.0f + expf(-logit));
        out[n] = (pr > 0.5f) ? 1.0f : 0.0f;
        out[NNODES + n] = pr;
    }
}

extern "C" void kernel_launch(void* const* d_in, const int* in_sizes, int n_in,
                              void* d_out, int out_size, void* d_ws, size_t ws_size,
                              hipStream_t stream) {
    const float* x_a       = (const float*)d_in[0];
    const int*   ei        = (const int*)d_in[1];    // [2, E]
    const float* edge_attr = (const float*)d_in[2];  // [E, 1]
    const float* g_w       = (const float*)d_in[3];  // [257,128]
    const float* g_b       = (const float*)d_in[4];  // [128]
    const float* f_w       = (const float*)d_in[5];  // [256,128]
    const float* f_b       = (const float*)d_in[6];  // [128]
    const float* cls_w     = (const float*)d_in[7];  // [128,1]
    const float* cls_b     = (const float*)d_in[8];  // [1]
    float* out = (float*)d_out;

    // workspace layout: part first (16B-aligned at ws base), then node scalars
    unsigned int* part = (unsigned int*)d_ws;                  // 128*2*10000 u32 = 10.24 MB
    float* xu   = (float*)d_ws + (size_t)NCHUNK * NNODES;      // N
    float* xp   = xu + NNODES;                                 // N
    float* r    = xp + NNODES;                                 // N
    float* scal = r + NNODES;                                  // 4

    k_node<<<NB1, BT, 0, stream>>>(x_a, g_w, g_b, f_w, f_b, cls_w, cls_b,
                                   xu, xp, r, scal);

    k_edge<<<NCHUNK * 2, BT, 0, stream>>>(ei, edge_attr, r, scal, part);

    k_final<<<(NNODES + 63) / 64, 256, 0, stream>>>(xu, xp, part, scal, out);
}